// Round 1
// baseline (890.789 us; speedup 1.0000x reference)
//
#include <hip/hip_runtime.h>
#include <hip/hip_bf16.h>
#include <cmath>

// Problem constants
#define BB 2
#define SS 2048
#define DD 512
#define HH 8
#define DKK 64
#define HWIN 128   // WIN/2

// ---------------------------------------------------------------------------
// fp32 GEMM: C[m,n] = sum_k A[m,k] * W[n,k] + bias[n]
// A: M x K row-major, W: N x K row-major (i.e. computes A @ W.T + b)
// Tile: 64x64 per block, 256 threads, 4x4 per thread, K-tile 16.
// ---------------------------------------------------------------------------
__global__ __launch_bounds__(256) void gemm_bias(
    const float* __restrict__ A,
    const float* __restrict__ W,
    const float* __restrict__ bias,
    float* __restrict__ C,
    int M, int N, int K)
{
    __shared__ float As[16][65];  // [k][m], padded to kill write conflicts
    __shared__ float Ws[16][65];  // [k][n]

    const int tid = threadIdx.x;       // 0..255
    const int tx  = tid & 15;          // n-group
    const int ty  = tid >> 4;          // m-group
    const int m0  = blockIdx.y * 64;
    const int n0  = blockIdx.x * 64;

    float acc[4][4] = {{0.f}};

    const int lr  = tid >> 2;          // 0..63 row within tile
    const int lc4 = (tid & 3) * 4;     // k offset 0,4,8,12

    for (int k0 = 0; k0 < K; k0 += 16) {
        {
            const float4 a = *(const float4*)(A + (size_t)(m0 + lr) * K + k0 + lc4);
            As[lc4 + 0][lr] = a.x; As[lc4 + 1][lr] = a.y;
            As[lc4 + 2][lr] = a.z; As[lc4 + 3][lr] = a.w;
            const float4 w = *(const float4*)(W + (size_t)(n0 + lr) * K + k0 + lc4);
            Ws[lc4 + 0][lr] = w.x; Ws[lc4 + 1][lr] = w.y;
            Ws[lc4 + 2][lr] = w.z; Ws[lc4 + 3][lr] = w.w;
        }
        __syncthreads();

        #pragma unroll
        for (int kk = 0; kk < 16; ++kk) {
            float a_[4], w_[4];
            #pragma unroll
            for (int i = 0; i < 4; ++i) a_[i] = As[kk][ty * 4 + i];
            #pragma unroll
            for (int j = 0; j < 4; ++j) w_[j] = Ws[kk][tx * 4 + j];
            #pragma unroll
            for (int i = 0; i < 4; ++i)
                #pragma unroll
                for (int j = 0; j < 4; ++j)
                    acc[i][j] += a_[i] * w_[j];
        }
        __syncthreads();
    }

    #pragma unroll
    for (int i = 0; i < 4; ++i) {
        const int m = m0 + ty * 4 + i;
        #pragma unroll
        for (int j = 0; j < 4; ++j) {
            const int n = n0 + tx * 4 + j;
            C[(size_t)m * N + n] = acc[i][j] + bias[n];
        }
    }
}

// ---------------------------------------------------------------------------
// Per-(b,h) column sums of V: VS[bh*64 + d] = sum_s V[b, s, h*64+d]
// ---------------------------------------------------------------------------
__global__ __launch_bounds__(256) void vsum_kernel(
    const float* __restrict__ V, float* __restrict__ VS)
{
    const int bh = blockIdx.x;          // 0..15
    const int h = bh & 7, b = bh >> 3;
    const int t = threadIdx.x;
    const int d = t & 63, g = t >> 6;   // 4 s-groups x 64 dims
    __shared__ float p[4][64];

    const size_t base = ((size_t)b * SS) * DD + (size_t)h * DKK;
    float acc = 0.f;
    for (int s = g; s < SS; s += 4)
        acc += V[base + (size_t)s * DD + d];
    p[g][d] = acc;
    __syncthreads();
    if (t < 64)
        VS[bh * 64 + t] = p[0][t] + p[1][t] + p[2][t] + p[3][t];
}

// ---------------------------------------------------------------------------
// Sliding-window attention with implicit-zero (not -inf) outside the band.
// One block (256 threads) per (b, h, query i).
// x_i = [ sum_{j in win} e^{s_j - m} v_j + e^{-m} (VS - sum_{j in win} v_j) ]
//       / [ sum_{j in win} e^{s_j - m} + (S - wcount) e^{-m} ],  m = max(0, max_j s_j)
// ---------------------------------------------------------------------------
__global__ __launch_bounds__(256) void attn_kernel(
    const float* __restrict__ Q, const float* __restrict__ K,
    const float* __restrict__ V, const float* __restrict__ VS,
    float* __restrict__ X)
{
    const int blk = blockIdx.x;
    const int i  = blk & (SS - 1);
    const int bh = blk >> 11;           // b*H + h
    const int h = bh & 7, b = bh >> 3;
    const int t = threadIdx.x;

    __shared__ float qs[64];
    __shared__ float sc[260];
    __shared__ float red[256];
    __shared__ float pev[4][64];
    __shared__ float pv[4][64];

    const float scale = 0.125f;         // 1/sqrt(64)

    const int jlo = max(0, i - HWIN);
    const int jhi = min(SS - 1, i + HWIN);
    const int wcount = jhi - jlo + 1;

    const size_t base = ((size_t)b * SS) * DD + (size_t)h * DKK;

    if (t < 64) qs[t] = Q[base + (size_t)i * DD + t];
    __syncthreads();

    // ---- scores over the window ----
    for (int jj = t; jj < wcount; jj += 256) {
        const float* kr = K + base + (size_t)(jlo + jj) * DD;
        float s = 0.f;
        #pragma unroll
        for (int d4 = 0; d4 < 64; d4 += 4) {
            const float4 kv = *(const float4*)(kr + d4);
            s += qs[d4] * kv.x + qs[d4 + 1] * kv.y
               + qs[d4 + 2] * kv.z + qs[d4 + 3] * kv.w;
        }
        sc[jj] = s * scale;
    }
    __syncthreads();

    // ---- max over {0} U scores ----
    float lmax = 0.0f;  // implicit-zero entries participate in the softmax
    for (int jj = t; jj < wcount; jj += 256) lmax = fmaxf(lmax, sc[jj]);
    red[t] = lmax;
    __syncthreads();
    for (int off = 128; off > 0; off >>= 1) {
        if (t < off) red[t] = fmaxf(red[t], red[t + off]);
        __syncthreads();
    }
    const float m = red[0];
    __syncthreads();

    // ---- exp + sum ----
    float lsum = 0.f;
    for (int jj = t; jj < wcount; jj += 256) {
        const float e = expf(sc[jj] - m);
        sc[jj] = e;
        lsum += e;
    }
    red[t] = lsum;
    __syncthreads();
    for (int off = 128; off > 0; off >>= 1) {
        if (t < off) red[t] += red[t + off];
        __syncthreads();
    }
    const float emneg = expf(-m);
    const float denom = red[0] + (float)(SS - wcount) * emneg;

    // ---- weighted V accumulation ----
    const int d = t & 63, g = t >> 6;
    float acc_ev = 0.f, acc_v = 0.f;
    for (int jj = g; jj < wcount; jj += 4) {
        const float vv = V[base + (size_t)(jlo + jj) * DD + d];
        acc_ev += sc[jj] * vv;
        acc_v  += vv;
    }
    pev[g][d] = acc_ev;
    pv[g][d]  = acc_v;
    __syncthreads();

    if (t < 64) {
        const float sev = pev[0][t] + pev[1][t] + pev[2][t] + pev[3][t];
        const float sv  = pv[0][t]  + pv[1][t]  + pv[2][t]  + pv[3][t];
        const float vs  = VS[bh * 64 + t];
        const float x = (sev + emneg * (vs - sv)) / denom;
        X[base + (size_t)i * DD + t] = x;
    }
}

// ---------------------------------------------------------------------------
extern "C" void kernel_launch(void* const* d_in, const int* in_sizes, int n_in,
                              void* d_out, int out_size, void* d_ws, size_t ws_size,
                              hipStream_t stream)
{
    const float* query  = (const float*)d_in[0];
    const float* key_in = (const float*)d_in[1];
    const float* value  = (const float*)d_in[2];
    const float* Wq = (const float*)d_in[3]; const float* bq = (const float*)d_in[4];
    const float* Wk = (const float*)d_in[5]; const float* bk = (const float*)d_in[6];
    const float* Wv = (const float*)d_in[7]; const float* bv = (const float*)d_in[8];
    const float* Wo = (const float*)d_in[9]; const float* bo = (const float*)d_in[10];
    float* out = (float*)d_out;

    const int M = BB * SS;              // 4096
    char* ws = (char*)d_ws;
    const size_t MB8 = (size_t)8 * 1024 * 1024;
    float* Qp = (float*)(ws);
    float* Kp = (float*)(ws + MB8);
    float* Vp = (float*)(ws + 2 * MB8);
    float* Xp = (float*)(ws + 3 * MB8);
    float* VS = (float*)(ws + 4 * MB8);

    dim3 gridG(DD / 64, M / 64);        // (8, 64)

    gemm_bias<<<gridG, 256, 0, stream>>>(query,  Wq, bq, Qp, M, DD, DD);
    gemm_bias<<<gridG, 256, 0, stream>>>(key_in, Wk, bk, Kp, M, DD, DD);
    gemm_bias<<<gridG, 256, 0, stream>>>(value,  Wv, bv, Vp, M, DD, DD);
    vsum_kernel<<<BB * HH, 256, 0, stream>>>(Vp, VS);
    attn_kernel<<<BB * HH * SS, 256, 0, stream>>>(Qp, Kp, Vp, VS, Xp);
    gemm_bias<<<gridG, 256, 0, stream>>>(Xp, Wo, bo, out, M, DD, DD);
}

// Round 4
// 315.557 us; speedup vs baseline: 2.8229x; 2.8229x over previous
//
#include <hip/hip_runtime.h>
#include <hip/hip_bf16.h>

#define SS 2048
#define DD 512
#define HWIN 128

typedef __bf16 bf16x8 __attribute__((ext_vector_type(8)));
typedef unsigned short u16x8 __attribute__((ext_vector_type(8)));
typedef float f32x4 __attribute__((ext_vector_type(4)));

__device__ __forceinline__ unsigned short f2bf(float x) {
    unsigned u = __builtin_bit_cast(unsigned, x);
    return (unsigned short)((u + 0x7fffu + ((u >> 16) & 1u)) >> 16);
}
__device__ __forceinline__ float bf2f(unsigned short s) {
    unsigned u = ((unsigned)s) << 16;
    return __builtin_bit_cast(float, u);
}
__device__ __forceinline__ void split_bf(float x, unsigned short& h, unsigned short& l) {
    h = f2bf(x);
    l = f2bf(x - bf2f(h));
}
__device__ __forceinline__ void split8(float4 f0, float4 f1, u16x8& h, u16x8& l) {
    const float vals[8] = {f0.x, f0.y, f0.z, f0.w, f1.x, f1.y, f1.z, f1.w};
    #pragma unroll
    for (int i = 0; i < 8; ++i) {
        unsigned short hh, ll;
        split_bf(vals[i], hh, ll);
        h[i] = hh;
        l[i] = ll;
    }
}
__device__ __forceinline__ f32x4 mfma16(u16x8 a, u16x8 b, f32x4 c) {
    return __builtin_amdgcn_mfma_f32_16x16x32_bf16(
        __builtin_bit_cast(bf16x8, a), __builtin_bit_cast(bf16x8, b), c, 0, 0, 0);
}

// ---------------------------------------------------------------------------
// Split-bf16 GEMM: C = A @ W.T + bias, M=4096 N=512 K=512.
// A is either fp32 (split in staging) or a bf16 hi/lo pair in ws.
// W is fp32 (split in staging). 3-product bf16x3: AhWh + AhWl + AlWh.
// Block 256 thr / 4 waves; tile 128x64; wave 64x32 (4x2 MFMA 16x16x32).
// LDS is fragment-contiguous (chunk (tile,lane) at (tile*64+lane)*8 elts).
// ---------------------------------------------------------------------------
template <bool A_FP32, bool OUT_SPLIT>
__device__ __forceinline__ void gemm_split_body(
    const float* __restrict__ Af,
    const unsigned short* __restrict__ AHg, const unsigned short* __restrict__ ALg,
    const float* __restrict__ W, const float* __restrict__ bias,
    unsigned short* __restrict__ OH, unsigned short* __restrict__ OL,
    float* __restrict__ OF)
{
    constexpr int K = 512, N = 512;
    __shared__ unsigned short Ah[8 * 64 * 8], Al[8 * 64 * 8];
    __shared__ unsigned short Bh[4 * 64 * 8], Bl[4 * 64 * 8];

    const int tid = threadIdx.x, wave = tid >> 6, lane = tid & 63;
    const int lm = lane & 15, lq = lane >> 4;
    const int m0 = blockIdx.y * 128, n0 = blockIdx.x * 64;
    const int wm = wave >> 1, wn = wave & 1;

    f32x4 acc[4][2] = {};

    const int ar0 = m0 + (wave * 2 + 0) * 16 + lm;
    const int ar1 = m0 + (wave * 2 + 1) * 16 + lm;
    const int br  = n0 + wave * 16 + lm;
    const int kb  = lq * 8;

    unsigned short* aD0h = &Ah[((wave * 2 + 0) * 64 + lane) * 8];
    unsigned short* aD1h = &Ah[((wave * 2 + 1) * 64 + lane) * 8];
    unsigned short* aD0l = &Al[((wave * 2 + 0) * 64 + lane) * 8];
    unsigned short* aD1l = &Al[((wave * 2 + 1) * 64 + lane) * 8];
    unsigned short* bDh  = &Bh[(wave * 64 + lane) * 8];
    unsigned short* bDl  = &Bl[(wave * 64 + lane) * 8];

    for (int k0 = 0; k0 < K; k0 += 32) {
        u16x8 a0h, a0l, a1h, a1l, b0h, b0l;
        if (A_FP32) {
            const float* p0 = Af + (size_t)ar0 * K + k0 + kb;
            split8(*(const float4*)p0, *(const float4*)(p0 + 4), a0h, a0l);
            const float* p1 = Af + (size_t)ar1 * K + k0 + kb;
            split8(*(const float4*)p1, *(const float4*)(p1 + 4), a1h, a1l);
        } else {
            a0h = *(const u16x8*)(AHg + (size_t)ar0 * K + k0 + kb);
            a0l = *(const u16x8*)(ALg + (size_t)ar0 * K + k0 + kb);
            a1h = *(const u16x8*)(AHg + (size_t)ar1 * K + k0 + kb);
            a1l = *(const u16x8*)(ALg + (size_t)ar1 * K + k0 + kb);
        }
        {
            const float* pw = W + (size_t)br * K + k0 + kb;
            split8(*(const float4*)pw, *(const float4*)(pw + 4), b0h, b0l);
        }
        __syncthreads();                 // previous iteration's frag reads done
        *(u16x8*)aD0h = a0h; *(u16x8*)aD0l = a0l;
        *(u16x8*)aD1h = a1h; *(u16x8*)aD1l = a1l;
        *(u16x8*)bDh  = b0h; *(u16x8*)bDl  = b0l;
        __syncthreads();

        u16x8 afh[4], afl[4], bfh[2], bfl[2];
        #pragma unroll
        for (int i = 0; i < 4; ++i) {
            afh[i] = *(const u16x8*)&Ah[((wm * 4 + i) * 64 + lane) * 8];
            afl[i] = *(const u16x8*)&Al[((wm * 4 + i) * 64 + lane) * 8];
        }
        #pragma unroll
        for (int j = 0; j < 2; ++j) {
            bfh[j] = *(const u16x8*)&Bh[((wn * 2 + j) * 64 + lane) * 8];
            bfl[j] = *(const u16x8*)&Bl[((wn * 2 + j) * 64 + lane) * 8];
        }
        #pragma unroll
        for (int i = 0; i < 4; ++i)
            #pragma unroll
            for (int j = 0; j < 2; ++j) {
                acc[i][j] = mfma16(afh[i], bfh[j], acc[i][j]);
                acc[i][j] = mfma16(afh[i], bfl[j], acc[i][j]);
                acc[i][j] = mfma16(afl[i], bfh[j], acc[i][j]);
            }
    }

    #pragma unroll
    for (int i = 0; i < 4; ++i)
        #pragma unroll
        for (int j = 0; j < 2; ++j) {
            const int col = n0 + (wn * 2 + j) * 16 + lm;
            const float bv = bias[col];
            #pragma unroll
            for (int r = 0; r < 4; ++r) {
                const int row = m0 + (wm * 4 + i) * 16 + lq * 4 + r;
                const float v = acc[i][j][r] + bv;
                if (OUT_SPLIT) {
                    unsigned short h, l;
                    split_bf(v, h, l);
                    OH[(size_t)row * N + col] = h;
                    OL[(size_t)row * N + col] = l;
                } else {
                    OF[(size_t)row * N + col] = v;
                }
            }
        }
}

__global__ __launch_bounds__(256) void proj_gemm(
    const float* __restrict__ q, const float* __restrict__ k, const float* __restrict__ v,
    const float* __restrict__ Wq, const float* __restrict__ Wk, const float* __restrict__ Wv,
    const float* __restrict__ bq, const float* __restrict__ bk, const float* __restrict__ bv,
    unsigned short* __restrict__ base)
{
    const int z = blockIdx.z;
    const float* A = (z == 0) ? q : ((z == 1) ? k : v);
    const float* W = (z == 0) ? Wq : ((z == 1) ? Wk : Wv);
    const float* bias = (z == 0) ? bq : ((z == 1) ? bk : bv);
    unsigned short* OH = base + (size_t)z * 4194304;
    unsigned short* OL = OH + 2097152;
    gemm_split_body<true, true>(A, nullptr, nullptr, W, bias, OH, OL, nullptr);
}

__global__ __launch_bounds__(256) void out_gemm(
    const unsigned short* __restrict__ XH, const unsigned short* __restrict__ XL,
    const float* __restrict__ Wo, const float* __restrict__ bo, float* __restrict__ O)
{
    gemm_split_body<false, false>(nullptr, XH, XL, Wo, bo, nullptr, nullptr, O);
}

// ---------------------------------------------------------------------------
// Per-(b,h) V column sums, fp32, from the hi/lo pair.
// ---------------------------------------------------------------------------
__global__ __launch_bounds__(256) void vsum_kernel(
    const unsigned short* __restrict__ VH, const unsigned short* __restrict__ VL,
    float* __restrict__ VS)
{
    const int bh = blockIdx.x, h = bh & 7, b = bh >> 3;
    const int t = threadIdx.x, d = t & 63, g = t >> 6;
    __shared__ float p[4][64];
    const size_t base = ((size_t)b * SS) * DD + (size_t)h * 64;
    float acc = 0.f;
    for (int s = g; s < SS; s += 4) {
        const size_t ix = base + (size_t)s * DD + d;
        acc += bf2f(VH[ix]) + bf2f(VL[ix]);
    }
    p[g][d] = acc;
    __syncthreads();
    if (t < 64) VS[bh * 64 + t] = p[0][t] + p[1][t] + p[2][t] + p[3][t];
}

// ---------------------------------------------------------------------------
// Split-bf16 MFMA sliding-window attention, implicit-zero softmax:
//   x = [ sum_win (e^s - 1) v + VS ] / ( 2048 + sum_win (e^s - 1) )
// Block = (b,h, 64-query tile); 5 j-tiles of 64 cover [i0-128, i0+191].
// All operands are hi/lo bf16 pairs; each product uses 3 MFMAs.
// ---------------------------------------------------------------------------
__global__ __launch_bounds__(256) void attn_mfma(
    const unsigned short* __restrict__ QH, const unsigned short* __restrict__ QL,
    const unsigned short* __restrict__ KH, const unsigned short* __restrict__ KL,
    const unsigned short* __restrict__ VH, const unsigned short* __restrict__ VL,
    const float* __restrict__ VS,
    unsigned short* __restrict__ XH, unsigned short* __restrict__ XL)
{
    const int bh = blockIdx.y, h = bh & 7, b = bh >> 3;
    const int i0 = blockIdx.x * 64;
    const int tid = threadIdx.x, wave = tid >> 6, lane = tid & 63;
    const int lm = lane & 15, lq = lane >> 4;
    const int kb = lq * 8;

    __shared__ unsigned short Kth[64][72], Ktl[64][72];   // [j][d]
    __shared__ unsigned short Vth[64][72], Vtl[64][72];   // [d][j] transposed
    __shared__ unsigned short Swh[64][72], Swl[64][72];   // [q][j]

    const size_t qoff = ((size_t)(b * SS + i0 + wave * 16 + lm)) * DD + h * 64 + kb;
    const u16x8 aQ0h = *(const u16x8*)(QH + qoff);
    const u16x8 aQ0l = *(const u16x8*)(QL + qoff);
    const u16x8 aQ1h = *(const u16x8*)(QH + qoff + 32);
    const u16x8 aQ1l = *(const u16x8*)(QL + qoff + 32);

    f32x4 oacc[4] = {};
    float dacc[4] = {0.f, 0.f, 0.f, 0.f};

    const int sr = tid & 63, sc = (tid >> 6) * 16;

    for (int jt = 0; jt < 5; ++jt) {
        const int jt0 = i0 - 128 + jt * 64;
        {
            const int j = jt0 + sr;
            u16x8 z = {0,0,0,0,0,0,0,0};
            u16x8 kh0 = z, kh1 = z, kl0 = z, kl1 = z;
            u16x8 vh0 = z, vh1 = z, vl0 = z, vl1 = z;
            if (j >= 0 && j < SS) {
                const size_t gb = ((size_t)(b * SS + j)) * DD + h * 64 + sc;
                kh0 = *(const u16x8*)(KH + gb); kh1 = *(const u16x8*)(KH + gb + 8);
                kl0 = *(const u16x8*)(KL + gb); kl1 = *(const u16x8*)(KL + gb + 8);
                vh0 = *(const u16x8*)(VH + gb); vh1 = *(const u16x8*)(VH + gb + 8);
                vl0 = *(const u16x8*)(VL + gb); vl1 = *(const u16x8*)(VL + gb + 8);
            }
            *(u16x8*)&Kth[sr][sc]     = kh0; *(u16x8*)&Kth[sr][sc + 8] = kh1;
            *(u16x8*)&Ktl[sr][sc]     = kl0; *(u16x8*)&Ktl[sr][sc + 8] = kl1;
            #pragma unroll
            for (int cc = 0; cc < 8; ++cc) {
                Vth[sc + cc][sr] = vh0[cc]; Vth[sc + 8 + cc][sr] = vh1[cc];
                Vtl[sc + cc][sr] = vl0[cc]; Vtl[sc + 8 + cc][sr] = vl1[cc];
            }
        }
        __syncthreads();

        #pragma unroll
        for (int js = 0; js < 4; ++js) {
            const int j0 = js * 16;
            const u16x8 bK0h = *(const u16x8*)&Kth[j0 + lm][kb];
            const u16x8 bK0l = *(const u16x8*)&Ktl[j0 + lm][kb];
            const u16x8 bK1h = *(const u16x8*)&Kth[j0 + lm][kb + 32];
            const u16x8 bK1l = *(const u16x8*)&Ktl[j0 + lm][kb + 32];
            f32x4 s = {0.f, 0.f, 0.f, 0.f};
            s = mfma16(aQ0h, bK0h, s);
            s = mfma16(aQ0h, bK0l, s);
            s = mfma16(aQ0l, bK0h, s);
            s = mfma16(aQ1h, bK1h, s);
            s = mfma16(aQ1h, bK1l, s);
            s = mfma16(aQ1l, bK1h, s);
            const int jg = jt0 + j0 + lm;
            const int iq = i0 + wave * 16 + lq * 4;
            #pragma unroll
            for (int r = 0; r < 4; ++r) {
                const int qi = iq + r;
                const bool in = (jg >= 0) && (jg < SS) &&
                                (jg >= qi - HWIN) && (jg <= qi + HWIN);
                const float w = in ? (__expf(s[r] * 0.125f) - 1.0f) : 0.0f;
                dacc[r] += w;
                unsigned short wh, wl;
                split_bf(w, wh, wl);
                Swh[wave * 16 + lq * 4 + r][j0 + lm] = wh;
                Swl[wave * 16 + lq * 4 + r][j0 + lm] = wl;
            }
        }
        __syncthreads();

        const u16x8 aP0h = *(const u16x8*)&Swh[wave * 16 + lm][kb];
        const u16x8 aP0l = *(const u16x8*)&Swl[wave * 16 + lm][kb];
        const u16x8 aP1h = *(const u16x8*)&Swh[wave * 16 + lm][kb + 32];
        const u16x8 aP1l = *(const u16x8*)&Swl[wave * 16 + lm][kb + 32];
        #pragma unroll
        for (int s4 = 0; s4 < 4; ++s4) {
            const u16x8 bV0h = *(const u16x8*)&Vth[s4 * 16 + lm][kb];
            const u16x8 bV0l = *(const u16x8*)&Vtl[s4 * 16 + lm][kb];
            const u16x8 bV1h = *(const u16x8*)&Vth[s4 * 16 + lm][kb + 32];
            const u16x8 bV1l = *(const u16x8*)&Vtl[s4 * 16 + lm][kb + 32];
            oacc[s4] = mfma16(aP0h, bV0h, oacc[s4]);
            oacc[s4] = mfma16(aP0l, bV0h, oacc[s4]);
            oacc[s4] = mfma16(aP0h, bV0l, oacc[s4]);
            oacc[s4] = mfma16(aP1h, bV1h, oacc[s4]);
            oacc[s4] = mfma16(aP1l, bV1h, oacc[s4]);
            oacc[s4] = mfma16(aP1h, bV1l, oacc[s4]);
        }
        __syncthreads();
    }

    #pragma unroll
    for (int r = 0; r < 4; ++r) {
        float v = dacc[r];
        v += __shfl_xor(v, 1);
        v += __shfl_xor(v, 2);
        v += __shfl_xor(v, 4);
        v += __shfl_xor(v, 8);
        dacc[r] = v + 2048.0f;
    }

    #pragma unroll
    for (int s4 = 0; s4 < 4; ++s4) {
        const float vsv = VS[bh * 64 + s4 * 16 + lm];
        #pragma unroll
        for (int r = 0; r < 4; ++r) {
            const int qrow = i0 + wave * 16 + lq * 4 + r;
            const float x = (oacc[s4][r] + vsv) / dacc[r];
            unsigned short xh, xl;
            split_bf(x, xh, xl);
            const size_t ix = ((size_t)(b * SS + qrow)) * DD + h * 64 + s4 * 16 + lm;
            XH[ix] = xh;
            XL[ix] = xl;
        }
    }
}

// ---------------------------------------------------------------------------
extern "C" void kernel_launch(void* const* d_in, const int* in_sizes, int n_in,
                              void* d_out, int out_size, void* d_ws, size_t ws_size,
                              hipStream_t stream)
{
    const float* query  = (const float*)d_in[0];
    const float* key_in = (const float*)d_in[1];
    const float* value  = (const float*)d_in[2];
    const float* Wq = (const float*)d_in[3]; const float* bq = (const float*)d_in[4];
    const float* Wk = (const float*)d_in[5]; const float* bk = (const float*)d_in[6];
    const float* Wv = (const float*)d_in[7]; const float* bv = (const float*)d_in[8];
    const float* Wo = (const float*)d_in[9]; const float* bo = (const float*)d_in[10];

    unsigned short* wsb = (unsigned short*)d_ws;
    // hi/lo pairs, 2,097,152 elts each: QH QL KH KL VH VL XH XL
    unsigned short* QH = wsb;
    unsigned short* QL = wsb + 2097152;
    unsigned short* KH = wsb + 4194304;
    unsigned short* KL = wsb + 6291456;
    unsigned short* VH = wsb + 8388608;
    unsigned short* VL = wsb + 10485760;
    unsigned short* XH = wsb + 12582912;
    unsigned short* XL = wsb + 14680064;
    float* VSp = (float*)((char*)d_ws + 33554432);   // 16*64 fp32

    proj_gemm<<<dim3(8, 32, 3), 256, 0, stream>>>(
        query, key_in, value, Wq, Wk, Wv, bq, bk, bv, QH);

    vsum_kernel<<<16, 256, 0, stream>>>(VH, VL, VSp);

    attn_mfma<<<dim3(32, 16), 256, 0, stream>>>(
        QH, QL, KH, KL, VH, VL, VSp, XH, XL);

    out_gemm<<<dim3(8, 32), 256, 0, stream>>>(XH, XL, Wo, bo, (float*)d_out);
}

// Round 5
// 177.351 us; speedup vs baseline: 5.0227x; 1.7793x over previous
//
#include <hip/hip_runtime.h>
#include <hip/hip_bf16.h>

#define SS 2048
#define DD 512
#define HWIN 128

typedef __bf16 bf16x8 __attribute__((ext_vector_type(8)));
typedef unsigned short u16x8 __attribute__((ext_vector_type(8)));
typedef float f32x4 __attribute__((ext_vector_type(4)));

__device__ __forceinline__ unsigned short f2bf(float x) {
    unsigned u = __builtin_bit_cast(unsigned, x);
    return (unsigned short)((u + 0x7fffu + ((u >> 16) & 1u)) >> 16);
}
__device__ __forceinline__ float bf2f(unsigned short s) {
    unsigned u = ((unsigned)s) << 16;
    return __builtin_bit_cast(float, u);
}
__device__ __forceinline__ void split_bf(float x, unsigned short& h, unsigned short& l) {
    h = f2bf(x);
    l = f2bf(x - bf2f(h));
}
__device__ __forceinline__ void split8(float4 f0, float4 f1, u16x8& h, u16x8& l) {
    const float vals[8] = {f0.x, f0.y, f0.z, f0.w, f1.x, f1.y, f1.z, f1.w};
    #pragma unroll
    for (int i = 0; i < 8; ++i) {
        unsigned short hh, ll;
        split_bf(vals[i], hh, ll);
        h[i] = hh;
        l[i] = ll;
    }
}
__device__ __forceinline__ f32x4 mfma16(u16x8 a, u16x8 b, f32x4 c) {
    return __builtin_amdgcn_mfma_f32_16x16x32_bf16(
        __builtin_bit_cast(bf16x8, a), __builtin_bit_cast(bf16x8, b), c, 0, 0, 0);
}

// ---------------------------------------------------------------------------
// Split-bf16 GEMM: C = A @ W.T + bias, M=4096 N=512 K=512.
// A is either fp32 (split in staging) or a bf16 hi/lo pair in ws.
// W is fp32 (split in staging). 3-product bf16x3: AhWh + AhWl + AlWh.
// Block 256 thr / 4 waves; tile 128x64; wave 64x32 (4x2 MFMA 16x16x32).
// LDS is fragment-contiguous (chunk (tile,lane) at (tile*64+lane)*8 elts).
// ---------------------------------------------------------------------------
template <bool A_FP32, bool OUT_SPLIT>
__device__ __forceinline__ void gemm_split_body(
    const float* __restrict__ Af,
    const unsigned short* __restrict__ AHg, const unsigned short* __restrict__ ALg,
    const float* __restrict__ W, const float* __restrict__ bias,
    unsigned short* __restrict__ OH, unsigned short* __restrict__ OL,
    float* __restrict__ OF)
{
    constexpr int K = 512, N = 512;
    __shared__ unsigned short Ah[8 * 64 * 8], Al[8 * 64 * 8];
    __shared__ unsigned short Bh[4 * 64 * 8], Bl[4 * 64 * 8];

    const int tid = threadIdx.x, wave = tid >> 6, lane = tid & 63;
    const int lm = lane & 15, lq = lane >> 4;
    const int m0 = blockIdx.y * 128, n0 = blockIdx.x * 64;
    const int wm = wave >> 1, wn = wave & 1;

    f32x4 acc[4][2] = {};

    const int ar0 = m0 + (wave * 2 + 0) * 16 + lm;
    const int ar1 = m0 + (wave * 2 + 1) * 16 + lm;
    const int br  = n0 + wave * 16 + lm;
    const int kb  = lq * 8;

    unsigned short* aD0h = &Ah[((wave * 2 + 0) * 64 + lane) * 8];
    unsigned short* aD1h = &Ah[((wave * 2 + 1) * 64 + lane) * 8];
    unsigned short* aD0l = &Al[((wave * 2 + 0) * 64 + lane) * 8];
    unsigned short* aD1l = &Al[((wave * 2 + 1) * 64 + lane) * 8];
    unsigned short* bDh  = &Bh[(wave * 64 + lane) * 8];
    unsigned short* bDl  = &Bl[(wave * 64 + lane) * 8];

    for (int k0 = 0; k0 < K; k0 += 32) {
        u16x8 a0h, a0l, a1h, a1l, b0h, b0l;
        if (A_FP32) {
            const float* p0 = Af + (size_t)ar0 * K + k0 + kb;
            split8(*(const float4*)p0, *(const float4*)(p0 + 4), a0h, a0l);
            const float* p1 = Af + (size_t)ar1 * K + k0 + kb;
            split8(*(const float4*)p1, *(const float4*)(p1 + 4), a1h, a1l);
        } else {
            a0h = *(const u16x8*)(AHg + (size_t)ar0 * K + k0 + kb);
            a0l = *(const u16x8*)(ALg + (size_t)ar0 * K + k0 + kb);
            a1h = *(const u16x8*)(AHg + (size_t)ar1 * K + k0 + kb);
            a1l = *(const u16x8*)(ALg + (size_t)ar1 * K + k0 + kb);
        }
        {
            const float* pw = W + (size_t)br * K + k0 + kb;
            split8(*(const float4*)pw, *(const float4*)(pw + 4), b0h, b0l);
        }
        __syncthreads();                 // previous iteration's frag reads done
        *(u16x8*)aD0h = a0h; *(u16x8*)aD0l = a0l;
        *(u16x8*)aD1h = a1h; *(u16x8*)aD1l = a1l;
        *(u16x8*)bDh  = b0h; *(u16x8*)bDl  = b0l;
        __syncthreads();

        u16x8 afh[4], afl[4], bfh[2], bfl[2];
        #pragma unroll
        for (int i = 0; i < 4; ++i) {
            afh[i] = *(const u16x8*)&Ah[((wm * 4 + i) * 64 + lane) * 8];
            afl[i] = *(const u16x8*)&Al[((wm * 4 + i) * 64 + lane) * 8];
        }
        #pragma unroll
        for (int j = 0; j < 2; ++j) {
            bfh[j] = *(const u16x8*)&Bh[((wn * 2 + j) * 64 + lane) * 8];
            bfl[j] = *(const u16x8*)&Bl[((wn * 2 + j) * 64 + lane) * 8];
        }
        #pragma unroll
        for (int i = 0; i < 4; ++i)
            #pragma unroll
            for (int j = 0; j < 2; ++j) {
                acc[i][j] = mfma16(afh[i], bfh[j], acc[i][j]);
                acc[i][j] = mfma16(afh[i], bfl[j], acc[i][j]);
                acc[i][j] = mfma16(afl[i], bfh[j], acc[i][j]);
            }
    }

    #pragma unroll
    for (int i = 0; i < 4; ++i)
        #pragma unroll
        for (int j = 0; j < 2; ++j) {
            const int col = n0 + (wn * 2 + j) * 16 + lm;
            const float bv = bias[col];
            #pragma unroll
            for (int r = 0; r < 4; ++r) {
                const int row = m0 + (wm * 4 + i) * 16 + lq * 4 + r;
                const float v = acc[i][j][r] + bv;
                if (OUT_SPLIT) {
                    unsigned short h, l;
                    split_bf(v, h, l);
                    OH[(size_t)row * N + col] = h;
                    OL[(size_t)row * N + col] = l;
                } else {
                    OF[(size_t)row * N + col] = v;
                }
            }
        }
}

__global__ __launch_bounds__(256) void proj_gemm(
    const float* __restrict__ q, const float* __restrict__ k, const float* __restrict__ v,
    const float* __restrict__ Wq, const float* __restrict__ Wk, const float* __restrict__ Wv,
    const float* __restrict__ bq, const float* __restrict__ bk, const float* __restrict__ bv,
    unsigned short* __restrict__ base)
{
    const int z = blockIdx.z;
    const float* A = (z == 0) ? q : ((z == 1) ? k : v);
    const float* W = (z == 0) ? Wq : ((z == 1) ? Wk : Wv);
    const float* bias = (z == 0) ? bq : ((z == 1) ? bk : bv);
    unsigned short* OH = base + (size_t)z * 4194304;
    unsigned short* OL = OH + 2097152;
    gemm_split_body<true, true>(A, nullptr, nullptr, W, bias, OH, OL, nullptr);
}

__global__ __launch_bounds__(256) void out_gemm(
    const unsigned short* __restrict__ XH, const unsigned short* __restrict__ XL,
    const float* __restrict__ Wo, const float* __restrict__ bo, float* __restrict__ O)
{
    gemm_split_body<false, false>(nullptr, XH, XL, Wo, bo, nullptr, nullptr, O);
}

// ---------------------------------------------------------------------------
// V column sums, two-stage. Stage 1: block (bh, chunk) sums 64 rows with
// coalesced loads -> partials. Stage 2: fold 32 chunks -> VS[bh*64+d].
// Partials live in the (not-yet-written) XH region: dead until attn_mfma,
// which launches after stage 2 completes (stream order).
// ---------------------------------------------------------------------------
__global__ __launch_bounds__(256) void vsum_stage1(
    const unsigned short* __restrict__ VH, const unsigned short* __restrict__ VL,
    float* __restrict__ partial)
{
    const int bh = blockIdx.x, c = blockIdx.y;
    const int h = bh & 7, b = bh >> 3;
    const int t = threadIdx.x, d = t & 63, g = t >> 6;
    __shared__ float p[4][64];
    const size_t base = ((size_t)b * SS + c * 64) * DD + (size_t)h * 64 + d;
    float acc = 0.f;
    #pragma unroll 4
    for (int s = g; s < 64; s += 4) {
        const size_t ix = base + (size_t)s * DD;
        acc += bf2f(VH[ix]) + bf2f(VL[ix]);
    }
    p[g][d] = acc;
    __syncthreads();
    if (t < 64)
        partial[((size_t)bh * 32 + c) * 64 + t] =
            p[0][t] + p[1][t] + p[2][t] + p[3][t];
}

__global__ __launch_bounds__(64) void vsum_stage2(
    const float* __restrict__ partial, float* __restrict__ VS)
{
    const int bh = blockIdx.x, d = threadIdx.x;
    float acc = 0.f;
    #pragma unroll 8
    for (int c = 0; c < 32; ++c)
        acc += partial[((size_t)bh * 32 + c) * 64 + d];
    VS[bh * 64 + d] = acc;
}

// ---------------------------------------------------------------------------
// Split-bf16 MFMA sliding-window attention, implicit-zero softmax:
//   x = [ sum_win (e^s - 1) v + VS ] / ( 2048 + sum_win (e^s - 1) )
// Block = (b,h, 64-query tile); 5 j-tiles of 64 cover [i0-128, i0+191].
// All operands are hi/lo bf16 pairs; each product uses 3 MFMAs.
// ---------------------------------------------------------------------------
__global__ __launch_bounds__(256) void attn_mfma(
    const unsigned short* __restrict__ QH, const unsigned short* __restrict__ QL,
    const unsigned short* __restrict__ KH, const unsigned short* __restrict__ KL,
    const unsigned short* __restrict__ VH, const unsigned short* __restrict__ VL,
    const float* __restrict__ VS,
    unsigned short* __restrict__ XH, unsigned short* __restrict__ XL)
{
    const int bh = blockIdx.y, h = bh & 7, b = bh >> 3;
    const int i0 = blockIdx.x * 64;
    const int tid = threadIdx.x, wave = tid >> 6, lane = tid & 63;
    const int lm = lane & 15, lq = lane >> 4;
    const int kb = lq * 8;

    __shared__ unsigned short Kth[64][72], Ktl[64][72];   // [j][d]
    __shared__ unsigned short Vth[64][72], Vtl[64][72];   // [d][j] transposed
    __shared__ unsigned short Swh[64][72], Swl[64][72];   // [q][j]

    const size_t qoff = ((size_t)(b * SS + i0 + wave * 16 + lm)) * DD + h * 64 + kb;
    const u16x8 aQ0h = *(const u16x8*)(QH + qoff);
    const u16x8 aQ0l = *(const u16x8*)(QL + qoff);
    const u16x8 aQ1h = *(const u16x8*)(QH + qoff + 32);
    const u16x8 aQ1l = *(const u16x8*)(QL + qoff + 32);

    f32x4 oacc[4] = {};
    float dacc[4] = {0.f, 0.f, 0.f, 0.f};

    const int sr = tid & 63, sc = (tid >> 6) * 16;

    for (int jt = 0; jt < 5; ++jt) {
        const int jt0 = i0 - 128 + jt * 64;
        {
            const int j = jt0 + sr;
            u16x8 z = {0,0,0,0,0,0,0,0};
            u16x8 kh0 = z, kh1 = z, kl0 = z, kl1 = z;
            u16x8 vh0 = z, vh1 = z, vl0 = z, vl1 = z;
            if (j >= 0 && j < SS) {
                const size_t gb = ((size_t)(b * SS + j)) * DD + h * 64 + sc;
                kh0 = *(const u16x8*)(KH + gb); kh1 = *(const u16x8*)(KH + gb + 8);
                kl0 = *(const u16x8*)(KL + gb); kl1 = *(const u16x8*)(KL + gb + 8);
                vh0 = *(const u16x8*)(VH + gb); vh1 = *(const u16x8*)(VH + gb + 8);
                vl0 = *(const u16x8*)(VL + gb); vl1 = *(const u16x8*)(VL + gb + 8);
            }
            *(u16x8*)&Kth[sr][sc]     = kh0; *(u16x8*)&Kth[sr][sc + 8] = kh1;
            *(u16x8*)&Ktl[sr][sc]     = kl0; *(u16x8*)&Ktl[sr][sc + 8] = kl1;
            #pragma unroll
            for (int cc = 0; cc < 8; ++cc) {
                Vth[sc + cc][sr] = vh0[cc]; Vth[sc + 8 + cc][sr] = vh1[cc];
                Vtl[sc + cc][sr] = vl0[cc]; Vtl[sc + 8 + cc][sr] = vl1[cc];
            }
        }
        __syncthreads();

        #pragma unroll
        for (int js = 0; js < 4; ++js) {
            const int j0 = js * 16;
            const u16x8 bK0h = *(const u16x8*)&Kth[j0 + lm][kb];
            const u16x8 bK0l = *(const u16x8*)&Ktl[j0 + lm][kb];
            const u16x8 bK1h = *(const u16x8*)&Kth[j0 + lm][kb + 32];
            const u16x8 bK1l = *(const u16x8*)&Ktl[j0 + lm][kb + 32];
            f32x4 s = {0.f, 0.f, 0.f, 0.f};
            s = mfma16(aQ0h, bK0h, s);
            s = mfma16(aQ0h, bK0l, s);
            s = mfma16(aQ0l, bK0h, s);
            s = mfma16(aQ1h, bK1h, s);
            s = mfma16(aQ1h, bK1l, s);
            s = mfma16(aQ1l, bK1h, s);
            const int jg = jt0 + j0 + lm;
            const int iq = i0 + wave * 16 + lq * 4;
            #pragma unroll
            for (int r = 0; r < 4; ++r) {
                const int qi = iq + r;
                const bool in = (jg >= 0) && (jg < SS) &&
                                (jg >= qi - HWIN) && (jg <= qi + HWIN);
                const float w = in ? (__expf(s[r] * 0.125f) - 1.0f) : 0.0f;
                dacc[r] += w;
                unsigned short wh, wl;
                split_bf(w, wh, wl);
                Swh[wave * 16 + lq * 4 + r][j0 + lm] = wh;
                Swl[wave * 16 + lq * 4 + r][j0 + lm] = wl;
            }
        }
        __syncthreads();

        const u16x8 aP0h = *(const u16x8*)&Swh[wave * 16 + lm][kb];
        const u16x8 aP0l = *(const u16x8*)&Swl[wave * 16 + lm][kb];
        const u16x8 aP1h = *(const u16x8*)&Swh[wave * 16 + lm][kb + 32];
        const u16x8 aP1l = *(const u16x8*)&Swl[wave * 16 + lm][kb + 32];
        #pragma unroll
        for (int s4 = 0; s4 < 4; ++s4) {
            const u16x8 bV0h = *(const u16x8*)&Vth[s4 * 16 + lm][kb];
            const u16x8 bV0l = *(const u16x8*)&Vtl[s4 * 16 + lm][kb];
            const u16x8 bV1h = *(const u16x8*)&Vth[s4 * 16 + lm][kb + 32];
            const u16x8 bV1l = *(const u16x8*)&Vtl[s4 * 16 + lm][kb + 32];
            oacc[s4] = mfma16(aP0h, bV0h, oacc[s4]);
            oacc[s4] = mfma16(aP0l, bV0h, oacc[s4]);
            oacc[s4] = mfma16(aP0h, bV0l, oacc[s4]);
            oacc[s4] = mfma16(aP1h, bV1h, oacc[s4]);
            oacc[s4] = mfma16(aP1l, bV1h, oacc[s4]);
            oacc[s4] = mfma16(aP1h, bV1l, oacc[s4]);
        }
        __syncthreads();
    }

    #pragma unroll
    for (int r = 0; r < 4; ++r) {
        float v = dacc[r];
        v += __shfl_xor(v, 1);
        v += __shfl_xor(v, 2);
        v += __shfl_xor(v, 4);
        v += __shfl_xor(v, 8);
        dacc[r] = v + 2048.0f;
    }

    #pragma unroll
    for (int s4 = 0; s4 < 4; ++s4) {
        const float vsv = VS[bh * 64 + s4 * 16 + lm];
        #pragma unroll
        for (int r = 0; r < 4; ++r) {
            const int qrow = i0 + wave * 16 + lq * 4 + r;
            const float x = (oacc[s4][r] + vsv) / dacc[r];
            unsigned short xh, xl;
            split_bf(x, xh, xl);
            const size_t ix = ((size_t)(b * SS + qrow)) * DD + h * 64 + s4 * 16 + lm;
            XH[ix] = xh;
            XL[ix] = xl;
        }
    }
}

// ---------------------------------------------------------------------------
extern "C" void kernel_launch(void* const* d_in, const int* in_sizes, int n_in,
                              void* d_out, int out_size, void* d_ws, size_t ws_size,
                              hipStream_t stream)
{
    const float* query  = (const float*)d_in[0];
    const float* key_in = (const float*)d_in[1];
    const float* value  = (const float*)d_in[2];
    const float* Wq = (const float*)d_in[3]; const float* bq = (const float*)d_in[4];
    const float* Wk = (const float*)d_in[5]; const float* bk = (const float*)d_in[6];
    const float* Wv = (const float*)d_in[7]; const float* bv = (const float*)d_in[8];
    const float* Wo = (const float*)d_in[9]; const float* bo = (const float*)d_in[10];

    unsigned short* wsb = (unsigned short*)d_ws;
    // hi/lo pairs, 2,097,152 elts each: QH QL KH KL VH VL XH XL
    unsigned short* QH = wsb;
    unsigned short* QL = wsb + 2097152;
    unsigned short* KH = wsb + 4194304;
    unsigned short* KL = wsb + 6291456;
    unsigned short* VH = wsb + 8388608;
    unsigned short* VL = wsb + 10485760;
    unsigned short* XH = wsb + 12582912;
    unsigned short* XL = wsb + 14680064;
    float* VSp = (float*)((char*)d_ws + 33554432);       // 16*64 fp32
    float* part = (float*)XH;  // 128 KB of partials; dead until attn_mfma runs

    proj_gemm<<<dim3(8, 32, 3), 256, 0, stream>>>(
        query, key_in, value, Wq, Wk, Wv, bq, bk, bv, QH);

    vsum_stage1<<<dim3(16, 32), 256, 0, stream>>>(VH, VL, part);
    vsum_stage2<<<16, 64, 0, stream>>>(part, VSp);

    attn_mfma<<<dim3(32, 16), 256, 0, stream>>>(
        QH, QL, KH, KL, VH, VL, VSp, XH, XL);

    out_gemm<<<dim3(8, 32), 256, 0, stream>>>(XH, XL, Wo, bo, (float*)d_out);
}

// Round 6
// 177.127 us; speedup vs baseline: 5.0291x; 1.0013x over previous
//
#include <hip/hip_runtime.h>
#include <hip/hip_bf16.h>

#define SS 2048
#define DD 512
#define HWIN 128

typedef __bf16 bf16x8 __attribute__((ext_vector_type(8)));
typedef unsigned short u16x8 __attribute__((ext_vector_type(8)));
typedef float f32x4 __attribute__((ext_vector_type(4)));

__device__ __forceinline__ unsigned short f2bf(float x) {
    unsigned u = __builtin_bit_cast(unsigned, x);
    return (unsigned short)((u + 0x7fffu + ((u >> 16) & 1u)) >> 16);
}
__device__ __forceinline__ float bf2f(unsigned short s) {
    unsigned u = ((unsigned)s) << 16;
    return __builtin_bit_cast(float, u);
}
__device__ __forceinline__ void split_bf(float x, unsigned short& h, unsigned short& l) {
    h = f2bf(x);
    l = f2bf(x - bf2f(h));
}
__device__ __forceinline__ void split8(float4 f0, float4 f1, u16x8& h, u16x8& l) {
    const float vals[8] = {f0.x, f0.y, f0.z, f0.w, f1.x, f1.y, f1.z, f1.w};
    #pragma unroll
    for (int i = 0; i < 8; ++i) {
        unsigned short hh, ll;
        split_bf(vals[i], hh, ll);
        h[i] = hh;
        l[i] = ll;
    }
}
__device__ __forceinline__ f32x4 mfma16(u16x8 a, u16x8 b, f32x4 c) {
    return __builtin_amdgcn_mfma_f32_16x16x32_bf16(
        __builtin_bit_cast(bf16x8, a), __builtin_bit_cast(bf16x8, b), c, 0, 0, 0);
}

// ---------------------------------------------------------------------------
// Cast Wq/Wk/Wv fp32 -> paired hi/lo bf16 ("paired": for each 8-elt chunk c,
// hi8 at u16 offset 2*e, lo8 at 2*e+8, e = 8c). 786432 elts total.
// ---------------------------------------------------------------------------
__global__ __launch_bounds__(256) void castW(
    const float* __restrict__ wq, const float* __restrict__ wk,
    const float* __restrict__ wv, unsigned short* __restrict__ dst)
{
    const size_t e0 = ((size_t)blockIdx.x * 256 + threadIdx.x) * 8;
    const float* src; size_t off;
    if      (e0 < 262144) { src = wq; off = e0; }
    else if (e0 < 524288) { src = wk; off = e0 - 262144; }
    else                  { src = wv; off = e0 - 524288; }
    u16x8 h, l;
    split8(*(const float4*)(src + off), *(const float4*)(src + off + 4), h, l);
    *(u16x8*)(dst + 2 * e0)     = h;
    *(u16x8*)(dst + 2 * e0 + 8) = l;
}

// ---------------------------------------------------------------------------
// Split-bf16 GEMM: C = A @ W.T + bias, M=4096 N=512 K=512.
// A: fp32 (split in staging) or bf16 hi/lo pair. B: paired-bf16 ws copy or
// fp32 (split in staging). 3-product bf16x3: AhWh + AhWl + AlWh.
// Block 256 thr / 4 waves; tile 128x64; wave 64x32 (4x2 MFMA 16x16x32).
// ---------------------------------------------------------------------------
template <bool A_FP32, bool B_PAIRED, bool OUT_SPLIT>
__device__ __forceinline__ void gemm_split_body(
    const float* __restrict__ Af,
    const unsigned short* __restrict__ AHg, const unsigned short* __restrict__ ALg,
    const unsigned short* __restrict__ Wp, const float* __restrict__ Wf,
    const float* __restrict__ bias,
    unsigned short* __restrict__ OH, unsigned short* __restrict__ OL,
    float* __restrict__ OF, int m0, int n0)
{
    constexpr int K = 512, N = 512;
    __shared__ unsigned short Ah[8 * 64 * 8], Al[8 * 64 * 8];
    __shared__ unsigned short Bh[4 * 64 * 8], Bl[4 * 64 * 8];

    const int tid = threadIdx.x, wave = tid >> 6, lane = tid & 63;
    const int lm = lane & 15, lq = lane >> 4;
    const int wm = wave >> 1, wn = wave & 1;

    f32x4 acc[4][2] = {};

    const int ar0 = m0 + (wave * 2 + 0) * 16 + lm;
    const int ar1 = m0 + (wave * 2 + 1) * 16 + lm;
    const int br  = n0 + wave * 16 + lm;
    const int kb  = lq * 8;

    unsigned short* aD0h = &Ah[((wave * 2 + 0) * 64 + lane) * 8];
    unsigned short* aD1h = &Ah[((wave * 2 + 1) * 64 + lane) * 8];
    unsigned short* aD0l = &Al[((wave * 2 + 0) * 64 + lane) * 8];
    unsigned short* aD1l = &Al[((wave * 2 + 1) * 64 + lane) * 8];
    unsigned short* bDh  = &Bh[(wave * 64 + lane) * 8];
    unsigned short* bDl  = &Bl[(wave * 64 + lane) * 8];

    for (int k0 = 0; k0 < K; k0 += 32) {
        u16x8 a0h, a0l, a1h, a1l, b0h, b0l;
        if (A_FP32) {
            const float* p0 = Af + (size_t)ar0 * K + k0 + kb;
            split8(*(const float4*)p0, *(const float4*)(p0 + 4), a0h, a0l);
            const float* p1 = Af + (size_t)ar1 * K + k0 + kb;
            split8(*(const float4*)p1, *(const float4*)(p1 + 4), a1h, a1l);
        } else {
            a0h = *(const u16x8*)(AHg + (size_t)ar0 * K + k0 + kb);
            a0l = *(const u16x8*)(ALg + (size_t)ar0 * K + k0 + kb);
            a1h = *(const u16x8*)(AHg + (size_t)ar1 * K + k0 + kb);
            a1l = *(const u16x8*)(ALg + (size_t)ar1 * K + k0 + kb);
        }
        if (B_PAIRED) {
            const unsigned short* pw = Wp + 2 * ((size_t)br * K + k0 + kb);
            b0h = *(const u16x8*)pw;
            b0l = *(const u16x8*)(pw + 8);
        } else {
            const float* pw = Wf + (size_t)br * K + k0 + kb;
            split8(*(const float4*)pw, *(const float4*)(pw + 4), b0h, b0l);
        }
        __syncthreads();                 // previous iteration's frag reads done
        *(u16x8*)aD0h = a0h; *(u16x8*)aD0l = a0l;
        *(u16x8*)aD1h = a1h; *(u16x8*)aD1l = a1l;
        *(u16x8*)bDh  = b0h; *(u16x8*)bDl  = b0l;
        __syncthreads();

        u16x8 afh[4], afl[4], bfh[2], bfl[2];
        #pragma unroll
        for (int i = 0; i < 4; ++i) {
            afh[i] = *(const u16x8*)&Ah[((wm * 4 + i) * 64 + lane) * 8];
            afl[i] = *(const u16x8*)&Al[((wm * 4 + i) * 64 + lane) * 8];
        }
        #pragma unroll
        for (int j = 0; j < 2; ++j) {
            bfh[j] = *(const u16x8*)&Bh[((wn * 2 + j) * 64 + lane) * 8];
            bfl[j] = *(const u16x8*)&Bl[((wn * 2 + j) * 64 + lane) * 8];
        }
        #pragma unroll
        for (int i = 0; i < 4; ++i)
            #pragma unroll
            for (int j = 0; j < 2; ++j) {
                acc[i][j] = mfma16(afh[i], bfh[j], acc[i][j]);
                acc[i][j] = mfma16(afh[i], bfl[j], acc[i][j]);
                acc[i][j] = mfma16(afl[i], bfh[j], acc[i][j]);
            }
    }

    #pragma unroll
    for (int i = 0; i < 4; ++i)
        #pragma unroll
        for (int j = 0; j < 2; ++j) {
            const int col = n0 + (wn * 2 + j) * 16 + lm;
            const float bv = bias[col];
            #pragma unroll
            for (int r = 0; r < 4; ++r) {
                const int row = m0 + (wm * 4 + i) * 16 + lq * 4 + r;
                const float v = acc[i][j][r] + bv;
                if (OUT_SPLIT) {
                    unsigned short h, l;
                    split_bf(v, h, l);
                    OH[(size_t)row * N + col] = h;
                    OL[(size_t)row * N + col] = l;
                } else {
                    OF[(size_t)row * N + col] = v;
                }
            }
        }
}

// 1D grid 768 with XCD swizzle: d = 64*(g/8) + 8x + (g%8), g = y*3+z.
// All 8 x-siblings (same A rows) share residue mod 8 -> same XCD L2.
__global__ __launch_bounds__(256) void proj_gemm(
    const float* __restrict__ q, const float* __restrict__ k, const float* __restrict__ v,
    const unsigned short* __restrict__ WP,
    const float* __restrict__ bq, const float* __restrict__ bk, const float* __restrict__ bv,
    unsigned short* __restrict__ base)
{
    const int d = blockIdx.x;
    const int hi = d >> 6, low = d & 63;
    const int x = low >> 3, r = low & 7;
    const int g = hi * 8 + r;            // 0..95
    const int y = g / 3, z = g - y * 3;

    const float* A = (z == 0) ? q : ((z == 1) ? k : v);
    const unsigned short* Wp = WP + (size_t)z * 524288;
    const float* bias = (z == 0) ? bq : ((z == 1) ? bk : bv);
    unsigned short* OH = base + (size_t)z * 4194304;
    unsigned short* OL = OH + 2097152;
    gemm_split_body<true, true, true>(A, nullptr, nullptr, Wp, nullptr, bias,
                                      OH, OL, nullptr, y * 128, x * 64);
}

// 1D grid 256 with XCD swizzle: d = 64*(y/8) + 8x + (y%8).
__global__ __launch_bounds__(256) void out_gemm(
    const unsigned short* __restrict__ XH, const unsigned short* __restrict__ XL,
    const float* __restrict__ Wo, const float* __restrict__ bo, float* __restrict__ O)
{
    const int d = blockIdx.x;
    const int hi = d >> 6, low = d & 63;
    const int x = low >> 3, r = low & 7;
    const int y = hi * 8 + r;            // 0..31
    gemm_split_body<false, false, false>(nullptr, XH, XL, nullptr, Wo, bo,
                                         nullptr, nullptr, O, y * 128, x * 64);
}

// ---------------------------------------------------------------------------
// V column sums, two-stage (partials parked in the dead XH region).
// ---------------------------------------------------------------------------
__global__ __launch_bounds__(256) void vsum_stage1(
    const unsigned short* __restrict__ VH, const unsigned short* __restrict__ VL,
    float* __restrict__ partial)
{
    const int bh = blockIdx.x, c = blockIdx.y;
    const int h = bh & 7, b = bh >> 3;
    const int t = threadIdx.x, d = t & 63, g = t >> 6;
    __shared__ float p[4][64];
    const size_t base = ((size_t)b * SS + c * 64) * DD + (size_t)h * 64 + d;
    float acc = 0.f;
    #pragma unroll 4
    for (int s = g; s < 64; s += 4) {
        const size_t ix = base + (size_t)s * DD;
        acc += bf2f(VH[ix]) + bf2f(VL[ix]);
    }
    p[g][d] = acc;
    __syncthreads();
    if (t < 64)
        partial[((size_t)bh * 32 + c) * 64 + t] =
            p[0][t] + p[1][t] + p[2][t] + p[3][t];
}

__global__ __launch_bounds__(64) void vsum_stage2(
    const float* __restrict__ partial, float* __restrict__ VS)
{
    const int bh = blockIdx.x, d = threadIdx.x;
    float acc = 0.f;
    #pragma unroll 8
    for (int c = 0; c < 32; ++c)
        acc += partial[((size_t)bh * 32 + c) * 64 + d];
    VS[bh * 64 + d] = acc;
}

// ---------------------------------------------------------------------------
// Split-bf16 MFMA sliding-window attention (unchanged math):
//   x = [ sum_win (e^s - 1) v + VS ] / ( 2048 + sum_win (e^s - 1) )
// 1D grid 512, XCD swizzle: d = 256*(bh/8) + 8*iblk + (bh%8) -> same-bh
// blocks share an XCD for K/V L2 reuse.
// ---------------------------------------------------------------------------
__global__ __launch_bounds__(256) void attn_mfma(
    const unsigned short* __restrict__ QH, const unsigned short* __restrict__ QL,
    const unsigned short* __restrict__ KH, const unsigned short* __restrict__ KL,
    const unsigned short* __restrict__ VH, const unsigned short* __restrict__ VL,
    const float* __restrict__ VS,
    unsigned short* __restrict__ XH, unsigned short* __restrict__ XL)
{
    const int dblk = blockIdx.x;
    const int bhi = dblk >> 8, blow = dblk & 255;
    const int xblk = blow >> 3, rr = blow & 7;
    const int bh = bhi * 8 + rr;         // 0..15
    const int h = bh & 7, b = bh >> 3;
    const int i0 = xblk * 64;
    const int tid = threadIdx.x, wave = tid >> 6, lane = tid & 63;
    const int lm = lane & 15, lq = lane >> 4;
    const int kb = lq * 8;

    __shared__ unsigned short Kth[64][72], Ktl[64][72];   // [j][d]
    __shared__ unsigned short Vth[64][72], Vtl[64][72];   // [d][j] transposed
    __shared__ unsigned short Swh[64][72], Swl[64][72];   // [q][j]

    const size_t qoff = ((size_t)(b * SS + i0 + wave * 16 + lm)) * DD + h * 64 + kb;
    const u16x8 aQ0h = *(const u16x8*)(QH + qoff);
    const u16x8 aQ0l = *(const u16x8*)(QL + qoff);
    const u16x8 aQ1h = *(const u16x8*)(QH + qoff + 32);
    const u16x8 aQ1l = *(const u16x8*)(QL + qoff + 32);

    f32x4 oacc[4] = {};
    float dacc[4] = {0.f, 0.f, 0.f, 0.f};

    const int sr = tid & 63, sc = (tid >> 6) * 16;

    for (int jt = 0; jt < 5; ++jt) {
        const int jt0 = i0 - 128 + jt * 64;
        {
            const int j = jt0 + sr;
            u16x8 z = {0,0,0,0,0,0,0,0};
            u16x8 kh0 = z, kh1 = z, kl0 = z, kl1 = z;
            u16x8 vh0 = z, vh1 = z, vl0 = z, vl1 = z;
            if (j >= 0 && j < SS) {
                const size_t gb = ((size_t)(b * SS + j)) * DD + h * 64 + sc;
                kh0 = *(const u16x8*)(KH + gb); kh1 = *(const u16x8*)(KH + gb + 8);
                kl0 = *(const u16x8*)(KL + gb); kl1 = *(const u16x8*)(KL + gb + 8);
                vh0 = *(const u16x8*)(VH + gb); vh1 = *(const u16x8*)(VH + gb + 8);
                vl0 = *(const u16x8*)(VL + gb); vl1 = *(const u16x8*)(VL + gb + 8);
            }
            *(u16x8*)&Kth[sr][sc]     = kh0; *(u16x8*)&Kth[sr][sc + 8] = kh1;
            *(u16x8*)&Ktl[sr][sc]     = kl0; *(u16x8*)&Ktl[sr][sc + 8] = kl1;
            #pragma unroll
            for (int cc = 0; cc < 8; ++cc) {
                Vth[sc + cc][sr] = vh0[cc]; Vth[sc + 8 + cc][sr] = vh1[cc];
                Vtl[sc + cc][sr] = vl0[cc]; Vtl[sc + 8 + cc][sr] = vl1[cc];
            }
        }
        __syncthreads();

        #pragma unroll
        for (int js = 0; js < 4; ++js) {
            const int j0 = js * 16;
            const u16x8 bK0h = *(const u16x8*)&Kth[j0 + lm][kb];
            const u16x8 bK0l = *(const u16x8*)&Ktl[j0 + lm][kb];
            const u16x8 bK1h = *(const u16x8*)&Kth[j0 + lm][kb + 32];
            const u16x8 bK1l = *(const u16x8*)&Ktl[j0 + lm][kb + 32];
            f32x4 s = {0.f, 0.f, 0.f, 0.f};
            s = mfma16(aQ0h, bK0h, s);
            s = mfma16(aQ0h, bK0l, s);
            s = mfma16(aQ0l, bK0h, s);
            s = mfma16(aQ1h, bK1h, s);
            s = mfma16(aQ1h, bK1l, s);
            s = mfma16(aQ1l, bK1h, s);
            const int jg = jt0 + j0 + lm;
            const int iq = i0 + wave * 16 + lq * 4;
            #pragma unroll
            for (int r = 0; r < 4; ++r) {
                const int qi = iq + r;
                const bool in = (jg >= 0) && (jg < SS) &&
                                (jg >= qi - HWIN) && (jg <= qi + HWIN);
                const float w = in ? (__expf(s[r] * 0.125f) - 1.0f) : 0.0f;
                dacc[r] += w;
                unsigned short wh, wl;
                split_bf(w, wh, wl);
                Swh[wave * 16 + lq * 4 + r][j0 + lm] = wh;
                Swl[wave * 16 + lq * 4 + r][j0 + lm] = wl;
            }
        }
        __syncthreads();

        const u16x8 aP0h = *(const u16x8*)&Swh[wave * 16 + lm][kb];
        const u16x8 aP0l = *(const u16x8*)&Swl[wave * 16 + lm][kb];
        const u16x8 aP1h = *(const u16x8*)&Swh[wave * 16 + lm][kb + 32];
        const u16x8 aP1l = *(const u16x8*)&Swl[wave * 16 + lm][kb + 32];
        #pragma unroll
        for (int s4 = 0; s4 < 4; ++s4) {
            const u16x8 bV0h = *(const u16x8*)&Vth[s4 * 16 + lm][kb];
            const u16x8 bV0l = *(const u16x8*)&Vtl[s4 * 16 + lm][kb];
            const u16x8 bV1h = *(const u16x8*)&Vth[s4 * 16 + lm][kb + 32];
            const u16x8 bV1l = *(const u16x8*)&Vtl[s4 * 16 + lm][kb + 32];
            oacc[s4] = mfma16(aP0h, bV0h, oacc[s4]);
            oacc[s4] = mfma16(aP0l, bV0h, oacc[s4]);
            oacc[s4] = mfma16(aP0h, bV0l, oacc[s4]);
            oacc[s4] = mfma16(aP1h, bV1h, oacc[s4]);
            oacc[s4] = mfma16(aP1l, bV1h, oacc[s4]);
            oacc[s4] = mfma16(aP1h, bV1l, oacc[s4]);
        }
        __syncthreads();
    }

    #pragma unroll
    for (int r = 0; r < 4; ++r) {
        float v = dacc[r];
        v += __shfl_xor(v, 1);
        v += __shfl_xor(v, 2);
        v += __shfl_xor(v, 4);
        v += __shfl_xor(v, 8);
        dacc[r] = v + 2048.0f;
    }

    #pragma unroll
    for (int s4 = 0; s4 < 4; ++s4) {
        const float vsv = VS[bh * 64 + s4 * 16 + lm];
        #pragma unroll
        for (int r = 0; r < 4; ++r) {
            const int qrow = i0 + wave * 16 + lq * 4 + r;
            const float x = (oacc[s4][r] + vsv) / dacc[r];
            unsigned short xh, xl;
            split_bf(x, xh, xl);
            const size_t ix = ((size_t)(b * SS + qrow)) * DD + h * 64 + s4 * 16 + lm;
            XH[ix] = xh;
            XL[ix] = xl;
        }
    }
}

// ---------------------------------------------------------------------------
extern "C" void kernel_launch(void* const* d_in, const int* in_sizes, int n_in,
                              void* d_out, int out_size, void* d_ws, size_t ws_size,
                              hipStream_t stream)
{
    const float* query  = (const float*)d_in[0];
    const float* key_in = (const float*)d_in[1];
    const float* value  = (const float*)d_in[2];
    const float* Wq = (const float*)d_in[3]; const float* bq = (const float*)d_in[4];
    const float* Wk = (const float*)d_in[5]; const float* bk = (const float*)d_in[6];
    const float* Wv = (const float*)d_in[7]; const float* bv = (const float*)d_in[8];
    const float* Wo = (const float*)d_in[9]; const float* bo = (const float*)d_in[10];

    unsigned short* wsb = (unsigned short*)d_ws;
    // hi/lo pairs, 2,097,152 u16 each: QH QL KH KL VH VL XH XL
    unsigned short* QH = wsb;
    unsigned short* QL = wsb + 2097152;
    unsigned short* KH = wsb + 4194304;
    unsigned short* KL = wsb + 6291456;
    unsigned short* VH = wsb + 8388608;
    unsigned short* VL = wsb + 10485760;
    unsigned short* XH = wsb + 12582912;
    unsigned short* XL = wsb + 14680064;
    float* VSp = (float*)((char*)d_ws + 33554432);       // 16*64 fp32
    // Transients parked inside the XH region (dead until attn_mfma writes it):
    unsigned short* WP = XH;                   // paired Wq/Wk/Wv: 1,572,864 u16
    float* part = (float*)(wsb + 14155776);    // vsum partials: 128 KB

    castW<<<384, 256, 0, stream>>>(Wq, Wk, Wv, WP);

    proj_gemm<<<768, 256, 0, stream>>>(
        query, key_in, value, WP, bq, bk, bv, QH);

    vsum_stage1<<<dim3(16, 32), 256, 0, stream>>>(VH, VL, part);
    vsum_stage2<<<16, 64, 0, stream>>>(part, VSp);

    attn_mfma<<<512, 256, 0, stream>>>(
        QH, QL, KH, KL, VH, VL, VSp, XH, XL);

    out_gemm<<<256, 256, 0, stream>>>(XH, XL, Wo, bo, (float*)d_out);
}